// Round 8
// baseline (521.890 us; speedup 1.0000x reference)
//
#include <hip/hip_runtime.h>
#include <math.h>

#define BB 256
#define DD 5120
#define NN 16
#define RR 160
#define CT 192          // 160 (t) + 16 (Bm) + 16 (Cm)
#define NSPLIT 64
#define KSPL 80         // K per split: 5120/64
#define TMP_ELEMS (BB * CT)          // 49152
#define NBLK 768
#define CTR_STRIDE 32   // one counter per 128 B

// init barrier counters (ws is re-poisoned to 0xAA before every call)
__global__ void kinit(int* ctr) {
    if (threadIdx.x < 3) ctr[threadIdx.x * CTR_STRIDE] = 0;
}

// device-scope arrive-and-wait barrier; all NBLK blocks co-resident
// (launch_bounds(256,3) x 256 CUs == 768 == grid size).
__device__ __forceinline__ void gbar(int* ctr) {
    __syncthreads();
    if (threadIdx.x == 0) {
        __threadfence();   // publish this block's writes device-wide
        __hip_atomic_fetch_add(ctr, 1, __ATOMIC_RELEASE, __HIP_MEMORY_SCOPE_AGENT);
        while (__hip_atomic_load(ctr, __ATOMIC_ACQUIRE, __HIP_MEMORY_SCOPE_AGENT) < NBLK) {
            __builtin_amdgcn_s_sleep(2);
        }
        __threadfence();   // invalidate stale caches before consuming
    }
    __syncthreads();
}

// One persistent kernel, 4 phases, 3 manual grid barriers.
__global__ __launch_bounds__(256, 3) void mega(const float* __restrict__ x,
                                               const float* __restrict__ h0,
                                               const float* __restrict__ Wxdt,
                                               const float* __restrict__ Wdt,
                                               const float* __restrict__ bdt,
                                               const float* __restrict__ Wbc,
                                               const float* __restrict__ Alog,
                                               float* __restrict__ out,
                                               float* __restrict__ part,
                                               float* __restrict__ tmp,
                                               float* __restrict__ dtb,
                                               int* __restrict__ ctr) {
    __shared__ float smem[32 * 34 + 32 * 64];   // 3136 floats, aliased per phase
    const int tid = threadIdx.x;
    const int bid = blockIdx.x;

    // ---------------- P1: GEMM1 split-K partials (12 tiles x 64 splits) -----
    {
        float* xs = smem;            // [16][68]
        float* ws = smem + 16 * 68;  // [16][64]
        const int tx = tid & 15, ty = tid >> 4;
        const int c0 = (bid % 3) * 64;
        const int b0 = ((bid / 3) & 3) * 64;
        const int s  = bid / 12;             // 0..63
        const int k0 = s * KSPL;
        float acc[4][4] = {};

        for (int kc = 0; kc < KSPL; kc += 16) {
            {
                const int row = tid >> 2;        // 0..63
                const int j4  = (tid & 3) * 4;   // 0,4,8,12
                const float4 v = *(const float4*)&x[(size_t)(b0 + row) * DD + k0 + kc + j4];
                xs[(j4 + 0) * 68 + row] = v.x;
                xs[(j4 + 1) * 68 + row] = v.y;
                xs[(j4 + 2) * 68 + row] = v.z;
                xs[(j4 + 3) * 68 + row] = v.w;
            }
            {
                const int r  = tid >> 4;         // 0..15
                const int c4 = (tid & 15) * 4;
                const int kg = k0 + kc + r;
                const int cg = c0 + c4;
                float4 v;
                if (cg < RR) v = *(const float4*)&Wxdt[(size_t)kg * RR + cg];
                else         v = *(const float4*)&Wbc[(size_t)kg * 32 + (cg - RR)];
                *(float4*)&ws[r * 64 + c4] = v;
            }
            __syncthreads();
            #pragma unroll
            for (int k = 0; k < 16; ++k) {
                const float4 a4 = *(const float4*)&xs[k * 68 + ty * 4];
                const float4 w4 = *(const float4*)&ws[k * 64 + tx * 4];
                const float av[4] = {a4.x, a4.y, a4.z, a4.w};
                const float wv[4] = {w4.x, w4.y, w4.z, w4.w};
                #pragma unroll
                for (int u = 0; u < 4; ++u)
                    #pragma unroll
                    for (int v = 0; v < 4; ++v)
                        acc[u][v] = fmaf(av[u], wv[v], acc[u][v]);
            }
            __syncthreads();
        }
        float* p = part + (size_t)s * TMP_ELEMS;
        #pragma unroll
        for (int u = 0; u < 4; ++u) {
            const int b = b0 + ty * 4 + u;
            *(float4*)&p[b * CT + c0 + tx * 4] =
                make_float4(acc[u][0], acc[u][1], acc[u][2], acc[u][3]);
        }
    }
    gbar(&ctr[0 * CTR_STRIDE]);

    // ---------------- P2: tmp = sum_s partials ----------------
    {
        const int idx = bid * 256 + tid;
        if (idx < TMP_ELEMS) {
            float sum = 0.f;
            #pragma unroll
            for (int z = 0; z < NSPLIT; ++z) sum += part[(size_t)z * TMP_ELEMS + idx];
            tmp[idx] = sum;
        }
    }
    gbar(&ctr[1 * CTR_STRIDE]);

    // ---------------- P3: dt = softplus(t @ Wdt + b_dt), 640 blocks --------
    if (bid < 640) {
        float* ts  = smem;            // [32][34]
        float* wsd = smem + 32 * 34;  // [32][64]
        const int tx = tid & 15, ty = tid >> 4;
        const int d0 = (bid % 80) * 64;
        const int b0 = (bid / 80) * 32;
        float acc[2][4] = {};

        for (int kc = 0; kc < RR; kc += 32) {
            {
                const int row = tid >> 3;         // 0..31 (b)
                const int j4  = (tid & 7) * 4;    // 0..28 (k)
                const float4 v = *(const float4*)&tmp[(size_t)(b0 + row) * CT + kc + j4];
                ts[(j4 + 0) * 34 + row] = v.x;
                ts[(j4 + 1) * 34 + row] = v.y;
                ts[(j4 + 2) * 34 + row] = v.z;
                ts[(j4 + 3) * 34 + row] = v.w;
            }
            {
                const int c4 = (tid & 15) * 4;
                const int r0 = tid >> 4;
                #pragma unroll
                for (int rep = 0; rep < 2; ++rep) {
                    const int r = r0 + rep * 16;
                    *(float4*)&wsd[r * 64 + c4] =
                        *(const float4*)&Wdt[(size_t)(kc + r) * DD + d0 + c4];
                }
            }
            __syncthreads();
            #pragma unroll
            for (int k = 0; k < 32; ++k) {
                const float a0 = ts[k * 34 + ty * 2 + 0];
                const float a1 = ts[k * 34 + ty * 2 + 1];
                const float4 w4 = *(const float4*)&wsd[k * 64 + tx * 4];
                const float wv[4] = {w4.x, w4.y, w4.z, w4.w};
                #pragma unroll
                for (int v = 0; v < 4; ++v) {
                    acc[0][v] = fmaf(a0, wv[v], acc[0][v]);
                    acc[1][v] = fmaf(a1, wv[v], acc[1][v]);
                }
            }
            __syncthreads();
        }
        const float4 bv = *(const float4*)&bdt[d0 + tx * 4];
        const float bb[4] = {bv.x, bv.y, bv.z, bv.w};
        #pragma unroll
        for (int u = 0; u < 2; ++u) {
            const int b = b0 + ty * 2 + u;
            float o[4];
            #pragma unroll
            for (int v = 0; v < 4; ++v) {
                const float z = acc[u][v] + bb[v];
                o[v] = fmaxf(z, 0.f) + log1pf(__expf(-fabsf(z)));
            }
            *(float4*)&dtb[(size_t)b * DD + d0 + tx * 4] = make_float4(o[0], o[1], o[2], o[3]);
        }
    }
    gbar(&ctr[2 * CTR_STRIDE]);

    // ---------------- P4: quad-cooperative h0 stream (1280 tiles) ----------
    {
        const int q = tid >> 2;                  // d within chunk
        const int l = tid & 3;                   // n-chunk (4 n's)
        for (int t = bid; t < 1280; t += NBLK) {
            const int d  = (t % 80) * 64 + q;
            const int b0 = (t / 80) * 16;
            const float4 av = *(const float4*)&Alog[(size_t)d * NN + l * 4];
            const float na[4] = {-__expf(av.x), -__expf(av.y), -__expf(av.z), -__expf(av.w)};

            #pragma unroll 4
            for (int bi = 0; bi < 16; ++bi) {
                const int b = b0 + bi;
                const size_t bd = (size_t)b * DD + d;
                const float4 h4 = *(const float4*)&h0[bd * NN + l * 4];
                const float dtv = dtb[bd];
                const float xv  = x[bd];
                const float4 bm4 = *(const float4*)&tmp[(size_t)b * CT + RR + l * 4];
                const float4 cm4 = *(const float4*)&tmp[(size_t)b * CT + RR + 16 + l * 4];
                const float dtx = dtv * xv;

                float p0, p1;
                p0 = fmaf(__expf(na[0] * dtv), h4.x, dtx * bm4.x) * cm4.x;
                p1 = fmaf(__expf(na[1] * dtv), h4.y, dtx * bm4.y) * cm4.y;
                p0 = fmaf(fmaf(__expf(na[2] * dtv), h4.z, dtx * bm4.z), cm4.z, p0);
                p1 = fmaf(fmaf(__expf(na[3] * dtv), h4.w, dtx * bm4.w), cm4.w, p1);
                float p = p0 + p1;
                p += __shfl_xor(p, 1);
                p += __shfl_xor(p, 2);
                if (l == 0) out[bd] = xv + p;
            }
        }
    }
}

extern "C" void kernel_launch(void* const* d_in, const int* in_sizes, int n_in,
                              void* d_out, int out_size, void* d_ws, size_t ws_size,
                              hipStream_t stream) {
    const float* x    = (const float*)d_in[0];
    const float* h0   = (const float*)d_in[1];
    const float* Wxdt = (const float*)d_in[2];
    const float* Wdt  = (const float*)d_in[3];
    const float* bdt  = (const float*)d_in[4];
    const float* Wbc  = (const float*)d_in[5];
    const float* Alog = (const float*)d_in[6];
    float* out = (float*)d_out;

    // ws layout (floats): partials[64*49152] | tmp[49152] | dt[1310720] | ctrs
    float* part = (float*)d_ws;
    float* tmp  = part + (size_t)NSPLIT * TMP_ELEMS;
    float* dtb  = tmp + TMP_ELEMS;
    int*   ctr  = (int*)(dtb + (size_t)BB * DD);

    kinit<<<1, 64, 0, stream>>>(ctr);
    mega<<<dim3(NBLK), dim3(256), 0, stream>>>(x, h0, Wxdt, Wdt, bdt, Wbc, Alog,
                                               out, part, tmp, dtb, ctr);
}